// Round 4
// baseline (2134.932 us; speedup 1.0000x reference)
//
#include <hip/hip_runtime.h>
#include <hip/hip_bf16.h>
#include <math.h>

// Sizes (fixed by the problem)
#define NB   8
#define NN   1024
#define HIDD 256
#define NHD  8
#define DHD  32
#define EPG  16384
#define KTOP 512

// out layout (f32 elements)
#define OUT_ENC   0
#define OUT_SUBX  2097152
#define OUT_SUBE  3145728
#define OUT_PERM  3407872
#define OUT_VALID 3411968

// ---------------- Fused QKV GEMM: 3x [8192x256]@[256x256] -----------------
__global__ __launch_bounds__(256) void gemm_qkv(
    const float* __restrict__ A,
    const float* __restrict__ W0, const float* __restrict__ W1,
    const float* __restrict__ W2,
    float* __restrict__ C0, float* __restrict__ C1, float* __restrict__ C2)
{
    __shared__ float As[32][68];
    __shared__ float Bs[32][68];
    int which = blockIdx.x >> 9;                 // 0,1,2
    const float* W = (which == 0) ? W0 : ((which == 1) ? W1 : W2);
    float*       C = (which == 0) ? C0 : ((which == 1) ? C1 : C2);
    int bid = blockIdx.x & 511;
    int t  = threadIdx.x;
    int bm = bid >> 2, bn = bid & 3;
    int m0 = bm * 64, n0 = bn * 64;
    int tx = t & 15, ty = t >> 4;
    float acc[4][4];
#pragma unroll
    for (int i = 0; i < 4; i++)
#pragma unroll
        for (int j = 0; j < 4; j++) acc[i][j] = 0.f;
    int am = t >> 2, ak = (t & 3) * 8;
    int bk = t >> 3, bn2 = (t & 7) * 8;
    for (int k0 = 0; k0 < 256; k0 += 32) {
        __syncthreads();
        float4 a0 = *(const float4*)(A + (m0 + am) * 256 + k0 + ak);
        float4 a1 = *(const float4*)(A + (m0 + am) * 256 + k0 + ak + 4);
        float4 b0 = *(const float4*)(W + (k0 + bk) * 256 + n0 + bn2);
        float4 b1 = *(const float4*)(W + (k0 + bk) * 256 + n0 + bn2 + 4);
        As[ak + 0][am] = a0.x; As[ak + 1][am] = a0.y;
        As[ak + 2][am] = a0.z; As[ak + 3][am] = a0.w;
        As[ak + 4][am] = a1.x; As[ak + 5][am] = a1.y;
        As[ak + 6][am] = a1.z; As[ak + 7][am] = a1.w;
        Bs[bk][bn2 + 0] = b0.x; Bs[bk][bn2 + 1] = b0.y;
        Bs[bk][bn2 + 2] = b0.z; Bs[bk][bn2 + 3] = b0.w;
        Bs[bk][bn2 + 4] = b1.x; Bs[bk][bn2 + 5] = b1.y;
        Bs[bk][bn2 + 6] = b1.z; Bs[bk][bn2 + 7] = b1.w;
        __syncthreads();
#pragma unroll
        for (int kk = 0; kk < 32; kk++) {
            float4 a4 = *(const float4*)&As[kk][ty * 4];
            float4 b4 = *(const float4*)&Bs[kk][tx * 4];
            float aa[4] = {a4.x, a4.y, a4.z, a4.w};
            float bb[4] = {b4.x, b4.y, b4.z, b4.w};
#pragma unroll
            for (int i = 0; i < 4; i++)
#pragma unroll
                for (int j = 0; j < 4; j++) acc[i][j] += aa[i] * bb[j];
        }
    }
#pragma unroll
    for (int i = 0; i < 4; i++) {
        float4 o = {acc[i][0], acc[i][1], acc[i][2], acc[i][3]};
        *(float4*)(C + (m0 + ty * 4 + i) * 256 + n0 + tx * 4) = o;
    }
}

// ------ GEMM writing two copies: xg (ws) and out ENC region (both f32) ----
__global__ __launch_bounds__(256) void gemm_f32_dual(
    const float* __restrict__ A, const float* __restrict__ W,
    float* __restrict__ Cf, float* __restrict__ Co)
{
    __shared__ float As[32][68];
    __shared__ float Bs[32][68];
    int t  = threadIdx.x;
    int bm = blockIdx.x >> 2, bn = blockIdx.x & 3;
    int m0 = bm * 64, n0 = bn * 64;
    int tx = t & 15, ty = t >> 4;
    float acc[4][4];
#pragma unroll
    for (int i = 0; i < 4; i++)
#pragma unroll
        for (int j = 0; j < 4; j++) acc[i][j] = 0.f;
    int am = t >> 2, ak = (t & 3) * 8;
    int bk = t >> 3, bn2 = (t & 7) * 8;
    for (int k0 = 0; k0 < 256; k0 += 32) {
        __syncthreads();
        float4 a0 = *(const float4*)(A + (m0 + am) * 256 + k0 + ak);
        float4 a1 = *(const float4*)(A + (m0 + am) * 256 + k0 + ak + 4);
        float4 b0 = *(const float4*)(W + (k0 + bk) * 256 + n0 + bn2);
        float4 b1 = *(const float4*)(W + (k0 + bk) * 256 + n0 + bn2 + 4);
        As[ak + 0][am] = a0.x; As[ak + 1][am] = a0.y;
        As[ak + 2][am] = a0.z; As[ak + 3][am] = a0.w;
        As[ak + 4][am] = a1.x; As[ak + 5][am] = a1.y;
        As[ak + 6][am] = a1.z; As[ak + 7][am] = a1.w;
        Bs[bk][bn2 + 0] = b0.x; Bs[bk][bn2 + 1] = b0.y;
        Bs[bk][bn2 + 2] = b0.z; Bs[bk][bn2 + 3] = b0.w;
        Bs[bk][bn2 + 4] = b1.x; Bs[bk][bn2 + 5] = b1.y;
        Bs[bk][bn2 + 6] = b1.z; Bs[bk][bn2 + 7] = b1.w;
        __syncthreads();
#pragma unroll
        for (int kk = 0; kk < 32; kk++) {
            float4 a4 = *(const float4*)&As[kk][ty * 4];
            float4 b4 = *(const float4*)&Bs[kk][tx * 4];
            float aa[4] = {a4.x, a4.y, a4.z, a4.w};
            float bb[4] = {b4.x, b4.y, b4.z, b4.w};
#pragma unroll
            for (int i = 0; i < 4; i++)
#pragma unroll
                for (int j = 0; j < 4; j++) acc[i][j] += aa[i] * bb[j];
        }
    }
#pragma unroll
    for (int i = 0; i < 4; i++) {
        int row = m0 + ty * 4 + i, col = n0 + tx * 4;
        float4 o = {acc[i][0], acc[i][1], acc[i][2], acc[i][3]};
        *(float4*)(Cf + row * 256 + col) = o;
        *(float4*)(Co + row * 256 + col) = o;
    }
}

// -------- Attention: split-K flash, 4 waves = 4 k-splits per block --------
// block = (b, h, qc in [0,16)); wave s handles k in [s*256, s*256+256)
// lane = one q row; K/V rows read from global (wave-uniform -> broadcast).
__global__ __launch_bounds__(256, 4) void attn_split(
    const float* __restrict__ Q, const float* __restrict__ Kf,
    const float* __restrict__ Vf, const float* __restrict__ dist,
    float* __restrict__ Ao)
{
    __shared__ float comb[4][64][34];
    int blk = blockIdx.x;                        // 1024 = 8 * 8 * 16
    int b = blk >> 7, h = (blk >> 4) & 7, qc = blk & 15;
    int t = threadIdx.x;
    int lane = t & 63, s = t >> 6;
    int q = qc * 64 + lane;
    const float* qp = Q + ((size_t)(b * NN + q)) * HIDD + h * DHD;
    float qv[32], acc[32];
#pragma unroll
    for (int u = 0; u < 8; u++) {
        float4 v4 = ((const float4*)qp)[u];
        qv[u * 4 + 0] = v4.x; qv[u * 4 + 1] = v4.y;
        qv[u * 4 + 2] = v4.z; qv[u * 4 + 3] = v4.w;
    }
#pragma unroll
    for (int u = 0; u < 32; u++) acc[u] = 0.f;
    float m = -INFINITY, l = 0.f;
    const float* dp = dist + ((size_t)(b * NN + q)) * NN;
    const float SCALE = 0.17677669529663687f;    // 1/sqrt(32)
    int kbeg = s * 256;
    for (int k0 = kbeg; k0 < kbeg + 256; k0 += 32) {
        float sc[32];
#pragma unroll
        for (int i = 0; i < 8; i++) {
            float4 dv = ((const float4*)(dp + k0))[i];
            sc[i * 4 + 0] = dv.x; sc[i * 4 + 1] = dv.y;
            sc[i * 4 + 2] = dv.z; sc[i * 4 + 3] = dv.w;
        }
        const float* kbase = Kf + ((size_t)(b * NN + k0)) * HIDD + h * DHD;
#pragma unroll
        for (int kk = 0; kk < 32; kk++) {
            const float4* kr = (const float4*)(kbase + kk * HIDD);
            float d = 0.f;
#pragma unroll
            for (int u = 0; u < 8; u++) {
                float4 kv = kr[u];
                d += qv[u * 4 + 0] * kv.x + qv[u * 4 + 1] * kv.y +
                     qv[u * 4 + 2] * kv.z + qv[u * 4 + 3] * kv.w;
            }
            sc[kk] += d * SCALE;
        }
        float tm = -INFINITY;
#pragma unroll
        for (int kk = 0; kk < 32; kk++) tm = fmaxf(tm, sc[kk]);
        float mnew = fmaxf(m, tm);
        float corr = __expf(m - mnew);
        l *= corr;
#pragma unroll
        for (int u = 0; u < 32; u++) acc[u] *= corr;
        const float* vbase = Vf + ((size_t)(b * NN + k0)) * HIDD + h * DHD;
#pragma unroll
        for (int kk = 0; kk < 32; kk++) {
            float p = __expf(sc[kk] - mnew);
            l += p;
            const float4* vr = (const float4*)(vbase + kk * HIDD);
#pragma unroll
            for (int u = 0; u < 8; u++) {
                float4 vv = vr[u];
                acc[u * 4 + 0] += p * vv.x; acc[u * 4 + 1] += p * vv.y;
                acc[u * 4 + 2] += p * vv.z; acc[u * 4 + 3] += p * vv.w;
            }
        }
        m = mnew;
    }
    comb[s][lane][0] = m;
    comb[s][lane][1] = l;
#pragma unroll
    for (int u = 0; u < 32; u++) comb[s][lane][2 + u] = acc[u];
    __syncthreads();
    if (s == 0) {
        float m0 = comb[0][lane][0], m1 = comb[1][lane][0];
        float m2 = comb[2][lane][0], m3 = comb[3][lane][0];
        float M = fmaxf(fmaxf(m0, m1), fmaxf(m2, m3));
        float w0 = __expf(m0 - M), w1 = __expf(m1 - M);
        float w2 = __expf(m2 - M), w3 = __expf(m3 - M);
        float L = comb[0][lane][1] * w0 + comb[1][lane][1] * w1 +
                  comb[2][lane][1] * w2 + comb[3][lane][1] * w3;
        float inv = 1.0f / L;
        float* op = Ao + ((size_t)(b * NN + q)) * HIDD + h * DHD;
#pragma unroll
        for (int u = 0; u < 8; u++) {
            float4 o4;
            o4.x = (comb[0][lane][2+u*4+0]*w0 + comb[1][lane][2+u*4+0]*w1 +
                    comb[2][lane][2+u*4+0]*w2 + comb[3][lane][2+u*4+0]*w3) * inv;
            o4.y = (comb[0][lane][2+u*4+1]*w0 + comb[1][lane][2+u*4+1]*w1 +
                    comb[2][lane][2+u*4+1]*w2 + comb[3][lane][2+u*4+1]*w3) * inv;
            o4.z = (comb[0][lane][2+u*4+2]*w0 + comb[1][lane][2+u*4+2]*w1 +
                    comb[2][lane][2+u*4+2]*w2 + comb[3][lane][2+u*4+2]*w3) * inv;
            o4.w = (comb[0][lane][2+u*4+3]*w0 + comb[1][lane][2+u*4+3]*w1 +
                    comb[2][lane][2+u*4+3]*w2 + comb[3][lane][2+u*4+3]*w3) * inv;
            ((float4*)op)[u] = o4;
        }
    }
}

// ---------------- TopK pool: scores + bitonic sort (per graph) ------------
__global__ __launch_bounds__(1024) void pool_topk(
    const float* __restrict__ xg, const float* __restrict__ w,
    float* __restrict__ out_perm, int* __restrict__ perm_int,
    float* __restrict__ vals_ws, int* __restrict__ nmap)
{
    __shared__ float wf[256];
    __shared__ float sv[1024];
    __shared__ unsigned long long keys[1024];
    __shared__ float nrm_s;
    int g = blockIdx.x, t = threadIdx.x;
    if (t < 256) wf[t] = w[t];
    nmap[g * 1024 + t] = -1;
    __syncthreads();
    if (t == 0) {
        float ss = 0.f;
        for (int c = 0; c < 256; c++) ss += wf[c] * wf[c];
        nrm_s = sqrtf(ss);
    }
    __syncthreads();
    float nrm = nrm_s;
    const float* xr = xg + ((size_t)(g * 1024 + t)) * 256;
    float dot = 0.f;
    for (int c = 0; c < 256; c += 4) {
        float4 x4 = *(const float4*)(xr + c);
        dot += x4.x * wf[c] + x4.y * wf[c + 1] + x4.z * wf[c + 2] + x4.w * wf[c + 3];
    }
    float s = tanhf(dot / nrm);
    sv[t] = s;
    unsigned u = __float_as_uint(s);
    u ^= (u >> 31) ? 0xFFFFFFFFu : 0x80000000u;
    keys[t] = (((unsigned long long)(~u)) << 32) | (unsigned)t;  // desc score, asc idx
    __syncthreads();
    for (unsigned k = 2; k <= 1024; k <<= 1) {
        for (unsigned j = k >> 1; j > 0; j >>= 1) {
            unsigned ixj = (unsigned)t ^ j;
            if (ixj > (unsigned)t) {
                unsigned long long a = keys[t], bb = keys[ixj];
                bool up = ((t & k) == 0);
                if (up ? (a > bb) : (a < bb)) { keys[t] = bb; keys[ixj] = a; }
            }
            __syncthreads();
        }
    }
    if (t < 512) {
        int idx = (int)(keys[t] & 1023u);
        out_perm[g * 512 + t] = (float)idx;
        perm_int[g * 512 + t] = idx;
        vals_ws[g * 512 + t] = sv[idx];
        nmap[g * 1024 + idx] = t;
    }
}

// ---------------- sub_x gather ------------------------------------------
__global__ __launch_bounds__(256) void gather_subx(
    const float* __restrict__ xg, const int* __restrict__ perm_int,
    const float* __restrict__ vals_ws, float* __restrict__ out_subx)
{
    int i4 = (blockIdx.x * 256 + threadIdx.x) * 4;   // < 1048576
    int b = i4 >> 17;
    int rem = i4 & 131071;
    int j = rem >> 8, c = rem & 255;
    int p = perm_int[b * 512 + j];
    float v = vals_ws[b * 512 + j];
    float4 x4 = *(const float4*)(xg + ((size_t)(b * 1024 + p)) * 256 + c);
    float4 o = {x4.x * v, x4.y * v, x4.z * v, x4.w * v};
    *(float4*)(out_subx + i4) = o;
}

// ---------------- Edge pipeline -----------------------------------------
__global__ __launch_bounds__(256) void zero_hist(int4* __restrict__ h) {
    h[blockIdx.x * 256 + threadIdx.x] = make_int4(0, 0, 0, 0);
}

__global__ __launch_bounds__(256) void edge_map(
    const int* __restrict__ e0, const int* __restrict__ e1,
    const int* __restrict__ nmap, int* __restrict__ H,
    int* __restrict__ key_e, int* __restrict__ r_e)
{
    int i = blockIdx.x * 256 + threadIdx.x;  // < 131072
    int g = i >> 14;
    int su = e0[i] - (g << 10);
    int sd = e1[i] - (g << 10);
    int nu = nmap[(g << 10) + su];
    int nv = nmap[(g << 10) + sd];
    if (nu >= 0 && nv >= 0) {
        int key = (nu << 9) | nv;
        int r = atomicAdd(&H[g * 262144 + key], 1);
        key_e[i] = key; r_e[i] = r;
    } else {
        key_e[i] = -1;
    }
}

__global__ __launch_bounds__(256) void scan_chunks(int* __restrict__ H,
                                                   int* __restrict__ ctot)
{
    __shared__ int scl[256];
    int t = threadIdx.x, blk = blockIdx.x;          // blk = g*256 + chunk
    int base = blk * 1024;
    int4 v = *(int4*)&H[base + t * 4];
    int s = v.x + v.y + v.z + v.w;
    scl[t] = s;
    __syncthreads();
    for (int off = 1; off < 256; off <<= 1) {
        int add = (t >= off) ? scl[t - off] : 0;
        __syncthreads();
        scl[t] += add;
        __syncthreads();
    }
    int incl = scl[t], excl = incl - s;
    int4 o; o.x = excl; o.y = excl + v.x; o.z = o.y + v.y; o.w = o.z + v.z;
    *(int4*)&H[base + t * 4] = o;
    if (t == 255) ctot[blk] = incl;
}

__global__ __launch_bounds__(256) void scan_tots(const int* __restrict__ ctot,
                                                 int* __restrict__ cbase)
{
    __shared__ int scl[256];
    int g = blockIdx.x, t = threadIdx.x;
    int v = ctot[g * 256 + t];
    scl[t] = v;
    __syncthreads();
    for (int off = 1; off < 256; off <<= 1) {
        int add = (t >= off) ? scl[t - off] : 0;
        __syncthreads();
        scl[t] += add;
        __syncthreads();
    }
    cbase[g * 256 + t] = scl[t] - v;
}

__global__ __launch_bounds__(256) void edge_out_init(float* __restrict__ o)
{
    int i = blockIdx.x * 256 + threadIdx.x;  // < 393216
    if (i < 262144) o[OUT_SUBE + i] = -1.0f;
    else            o[OUT_VALID + (i - 262144)] = 0.0f;
}

__global__ __launch_bounds__(256) void edge_out_write(
    const int* __restrict__ key_e, const int* __restrict__ r_e,
    const int* __restrict__ H, const int* __restrict__ cbase,
    float* __restrict__ o)
{
    int i = blockIdx.x * 256 + threadIdx.x;
    int key = key_e[i];
    if (key < 0) return;
    int g = i >> 14;
    int pos = H[g * 262144 + key] + cbase[(g << 8) + (key >> 10)] + r_e[i];
    int nu = key >> 9, nv = key & 511;
    o[OUT_SUBE + (g * 2 + 0) * 16384 + pos] = (float)nu;
    o[OUT_SUBE + (g * 2 + 1) * 16384 + pos] = (float)nv;
    o[OUT_VALID + g * 16384 + pos] = 1.0f;
}

// -------------------------------------------------------------------------
extern "C" void kernel_launch(void* const* d_in, const int* in_sizes, int n_in,
                              void* d_out, int out_size, void* d_ws, size_t ws_size,
                              hipStream_t stream)
{
    const float* x    = (const float*)d_in[0];
    const int*   eidx = (const int*)d_in[1];
    const float* dist = (const float*)d_in[3];
    const float* Wq   = (const float*)d_in[5];
    const float* Wk   = (const float*)d_in[6];
    const float* Wv   = (const float*)d_in[7];
    const float* Wo   = (const float*)d_in[8];
    const float* tw   = (const float*)d_in[9];

    char* ws = (char*)d_ws;
    // Region A [0,8MB): Q, later xg (f32 encoder result)
    // Region B [8,16MB): K, later hist
    // Region C [16,24MB): V, later edge scratch + pool scratch
    // Region D [24,32MB): attn_out
    float* Qf = (float*)(ws);
    float* Kf = (float*)(ws + (8u << 20));
    float* Vf = (float*)(ws + (16u << 20));
    float* Ao = (float*)(ws + (24u << 20));
    float* xg = Qf;
    int*   H  = (int*)Kf;
    char*  cb = ws + (16u << 20);
    int*   key_e = (int*)(cb);
    int*   r_e   = (int*)(cb + (512u << 10));
    int*   ctot  = (int*)(cb + (1024u << 10));
    int*   cbas  = (int*)(cb + (1024u << 10) + 8192);
    int*   permi = (int*)(cb + (1024u << 10) + 16384);
    float* vals  = (float*)(cb + (1024u << 10) + 32768);
    int*   nmap  = (int*)(cb + (1024u << 10) + 49152);
    float* out = (float*)d_out;

    gemm_qkv<<<1536, 256, 0, stream>>>(x, Wq, Wk, Wv, Qf, Kf, Vf);
    attn_split<<<1024, 256, 0, stream>>>(Qf, Kf, Vf, dist, Ao);
    gemm_f32_dual<<<512, 256, 0, stream>>>(Ao, Wo, xg, out + OUT_ENC);
    pool_topk<<<8, 1024, 0, stream>>>(xg, tw, out + OUT_PERM, permi, vals, nmap);
    zero_hist<<<2048, 256, 0, stream>>>((int4*)H);
    edge_map<<<512, 256, 0, stream>>>(eidx, eidx + 131072, nmap, H, key_e, r_e);
    scan_chunks<<<2048, 256, 0, stream>>>(H, ctot);
    scan_tots<<<8, 256, 0, stream>>>(ctot, cbas);
    edge_out_init<<<1536, 256, 0, stream>>>(out);
    edge_out_write<<<512, 256, 0, stream>>>(key_e, r_e, H, cbas, out);
    gather_subx<<<1024, 256, 0, stream>>>(xg, permi, vals, out + OUT_SUBX);
}

// Round 5
// 1172.062 us; speedup vs baseline: 1.8215x; 1.8215x over previous
//
#include <hip/hip_runtime.h>
#include <hip/hip_bf16.h>
#include <math.h>

// Sizes (fixed by the problem)
#define NB   8
#define NN   1024
#define HIDD 256
#define NHD  8
#define DHD  32
#define EPG  16384
#define KTOP 512

// out layout (f32 elements)
#define OUT_ENC   0
#define OUT_SUBX  2097152
#define OUT_SUBE  3145728
#define OUT_PERM  3407872
#define OUT_VALID 3411968

// ---------------- Fused QKV GEMM: 3x [8192x256]@[256x256] -----------------
__global__ __launch_bounds__(256) void gemm_qkv(
    const float* __restrict__ A,
    const float* __restrict__ W0, const float* __restrict__ W1,
    const float* __restrict__ W2,
    float* __restrict__ C0, float* __restrict__ C1, float* __restrict__ C2)
{
    __shared__ float As[32][68];
    __shared__ float Bs[32][68];
    int which = blockIdx.x >> 9;                 // 0,1,2
    const float* W = (which == 0) ? W0 : ((which == 1) ? W1 : W2);
    float*       C = (which == 0) ? C0 : ((which == 1) ? C1 : C2);
    int bid = blockIdx.x & 511;
    int t  = threadIdx.x;
    int bm = bid >> 2, bn = bid & 3;
    int m0 = bm * 64, n0 = bn * 64;
    int tx = t & 15, ty = t >> 4;
    float acc[4][4];
#pragma unroll
    for (int i = 0; i < 4; i++)
#pragma unroll
        for (int j = 0; j < 4; j++) acc[i][j] = 0.f;
    int am = t >> 2, ak = (t & 3) * 8;
    int bk = t >> 3, bn2 = (t & 7) * 8;
    for (int k0 = 0; k0 < 256; k0 += 32) {
        __syncthreads();
        float4 a0 = *(const float4*)(A + (m0 + am) * 256 + k0 + ak);
        float4 a1 = *(const float4*)(A + (m0 + am) * 256 + k0 + ak + 4);
        float4 b0 = *(const float4*)(W + (k0 + bk) * 256 + n0 + bn2);
        float4 b1 = *(const float4*)(W + (k0 + bk) * 256 + n0 + bn2 + 4);
        As[ak + 0][am] = a0.x; As[ak + 1][am] = a0.y;
        As[ak + 2][am] = a0.z; As[ak + 3][am] = a0.w;
        As[ak + 4][am] = a1.x; As[ak + 5][am] = a1.y;
        As[ak + 6][am] = a1.z; As[ak + 7][am] = a1.w;
        Bs[bk][bn2 + 0] = b0.x; Bs[bk][bn2 + 1] = b0.y;
        Bs[bk][bn2 + 2] = b0.z; Bs[bk][bn2 + 3] = b0.w;
        Bs[bk][bn2 + 4] = b1.x; Bs[bk][bn2 + 5] = b1.y;
        Bs[bk][bn2 + 6] = b1.z; Bs[bk][bn2 + 7] = b1.w;
        __syncthreads();
#pragma unroll
        for (int kk = 0; kk < 32; kk++) {
            float4 a4 = *(const float4*)&As[kk][ty * 4];
            float4 b4 = *(const float4*)&Bs[kk][tx * 4];
            float aa[4] = {a4.x, a4.y, a4.z, a4.w};
            float bb[4] = {b4.x, b4.y, b4.z, b4.w};
#pragma unroll
            for (int i = 0; i < 4; i++)
#pragma unroll
                for (int j = 0; j < 4; j++) acc[i][j] += aa[i] * bb[j];
        }
    }
#pragma unroll
    for (int i = 0; i < 4; i++) {
        float4 o = {acc[i][0], acc[i][1], acc[i][2], acc[i][3]};
        *(float4*)(C + (m0 + ty * 4 + i) * 256 + n0 + tx * 4) = o;
    }
}

// ------ GEMM writing two copies: xg (ws) and out ENC region (both f32) ----
__global__ __launch_bounds__(256) void gemm_f32_dual(
    const float* __restrict__ A, const float* __restrict__ W,
    float* __restrict__ Cf, float* __restrict__ Co)
{
    __shared__ float As[32][68];
    __shared__ float Bs[32][68];
    int t  = threadIdx.x;
    int bm = blockIdx.x >> 2, bn = blockIdx.x & 3;
    int m0 = bm * 64, n0 = bn * 64;
    int tx = t & 15, ty = t >> 4;
    float acc[4][4];
#pragma unroll
    for (int i = 0; i < 4; i++)
#pragma unroll
        for (int j = 0; j < 4; j++) acc[i][j] = 0.f;
    int am = t >> 2, ak = (t & 3) * 8;
    int bk = t >> 3, bn2 = (t & 7) * 8;
    for (int k0 = 0; k0 < 256; k0 += 32) {
        __syncthreads();
        float4 a0 = *(const float4*)(A + (m0 + am) * 256 + k0 + ak);
        float4 a1 = *(const float4*)(A + (m0 + am) * 256 + k0 + ak + 4);
        float4 b0 = *(const float4*)(W + (k0 + bk) * 256 + n0 + bn2);
        float4 b1 = *(const float4*)(W + (k0 + bk) * 256 + n0 + bn2 + 4);
        As[ak + 0][am] = a0.x; As[ak + 1][am] = a0.y;
        As[ak + 2][am] = a0.z; As[ak + 3][am] = a0.w;
        As[ak + 4][am] = a1.x; As[ak + 5][am] = a1.y;
        As[ak + 6][am] = a1.z; As[ak + 7][am] = a1.w;
        Bs[bk][bn2 + 0] = b0.x; Bs[bk][bn2 + 1] = b0.y;
        Bs[bk][bn2 + 2] = b0.z; Bs[bk][bn2 + 3] = b0.w;
        Bs[bk][bn2 + 4] = b1.x; Bs[bk][bn2 + 5] = b1.y;
        Bs[bk][bn2 + 6] = b1.z; Bs[bk][bn2 + 7] = b1.w;
        __syncthreads();
#pragma unroll
        for (int kk = 0; kk < 32; kk++) {
            float4 a4 = *(const float4*)&As[kk][ty * 4];
            float4 b4 = *(const float4*)&Bs[kk][tx * 4];
            float aa[4] = {a4.x, a4.y, a4.z, a4.w};
            float bb[4] = {b4.x, b4.y, b4.z, b4.w};
#pragma unroll
            for (int i = 0; i < 4; i++)
#pragma unroll
                for (int j = 0; j < 4; j++) acc[i][j] += aa[i] * bb[j];
        }
    }
#pragma unroll
    for (int i = 0; i < 4; i++) {
        int row = m0 + ty * 4 + i, col = n0 + tx * 4;
        float4 o = {acc[i][0], acc[i][1], acc[i][2], acc[i][3]};
        *(float4*)(Cf + row * 256 + col) = o;
        *(float4*)(Co + row * 256 + col) = o;
    }
}

// -------- Attention: split-K flash, 4 waves = 4 k-splits per block --------
// block = (b, h, qc in [0,16)); wave s handles k in [s*256, s*256+256)
// lane = one q row; K/V rows read from global (wave-uniform -> broadcast).
// NOTE: no min-wave clamp -- (256,4) capped VGPRs at 64 and spilled (R4:
// WRITE_SIZE 3.4 GB of scratch). Let the allocator take ~120 VGPRs.
__global__ __launch_bounds__(256) void attn_split(
    const float* __restrict__ Q, const float* __restrict__ Kf,
    const float* __restrict__ Vf, const float* __restrict__ dist,
    float* __restrict__ Ao)
{
    __shared__ float comb[4][64][34];
    int blk = blockIdx.x;                        // 1024 = 8 * 8 * 16
    int b = blk >> 7, h = (blk >> 4) & 7, qc = blk & 15;
    int t = threadIdx.x;
    int lane = t & 63, s = t >> 6;
    int q = qc * 64 + lane;
    const float* qp = Q + ((size_t)(b * NN + q)) * HIDD + h * DHD;
    float qv[32], acc[32];
#pragma unroll
    for (int u = 0; u < 8; u++) {
        float4 v4 = ((const float4*)qp)[u];
        qv[u * 4 + 0] = v4.x; qv[u * 4 + 1] = v4.y;
        qv[u * 4 + 2] = v4.z; qv[u * 4 + 3] = v4.w;
    }
#pragma unroll
    for (int u = 0; u < 32; u++) acc[u] = 0.f;
    float m = -INFINITY, l = 0.f;
    const float* dp = dist + ((size_t)(b * NN + q)) * NN;
    const float SCALE = 0.17677669529663687f;    // 1/sqrt(32)
    int kbeg = s * 256;
    for (int k0 = kbeg; k0 < kbeg + 256; k0 += 32) {
        float sc[32];
#pragma unroll
        for (int i = 0; i < 8; i++) {
            float4 dv = ((const float4*)(dp + k0))[i];
            sc[i * 4 + 0] = dv.x; sc[i * 4 + 1] = dv.y;
            sc[i * 4 + 2] = dv.z; sc[i * 4 + 3] = dv.w;
        }
        const float* kbase = Kf + ((size_t)(b * NN + k0)) * HIDD + h * DHD;
#pragma unroll
        for (int kk = 0; kk < 32; kk++) {
            const float4* kr = (const float4*)(kbase + kk * HIDD);
            float d = 0.f;
#pragma unroll
            for (int u = 0; u < 8; u++) {
                float4 kv = kr[u];
                d += qv[u * 4 + 0] * kv.x + qv[u * 4 + 1] * kv.y +
                     qv[u * 4 + 2] * kv.z + qv[u * 4 + 3] * kv.w;
            }
            sc[kk] += d * SCALE;
        }
        float tm = -INFINITY;
#pragma unroll
        for (int kk = 0; kk < 32; kk++) tm = fmaxf(tm, sc[kk]);
        float mnew = fmaxf(m, tm);
        float corr = __expf(m - mnew);
        l *= corr;
#pragma unroll
        for (int u = 0; u < 32; u++) acc[u] *= corr;
        const float* vbase = Vf + ((size_t)(b * NN + k0)) * HIDD + h * DHD;
#pragma unroll
        for (int kk = 0; kk < 32; kk++) {
            float p = __expf(sc[kk] - mnew);
            l += p;
            const float4* vr = (const float4*)(vbase + kk * HIDD);
#pragma unroll
            for (int u = 0; u < 8; u++) {
                float4 vv = vr[u];
                acc[u * 4 + 0] += p * vv.x; acc[u * 4 + 1] += p * vv.y;
                acc[u * 4 + 2] += p * vv.z; acc[u * 4 + 3] += p * vv.w;
            }
        }
        m = mnew;
    }
    comb[s][lane][0] = m;
    comb[s][lane][1] = l;
#pragma unroll
    for (int u = 0; u < 32; u++) comb[s][lane][2 + u] = acc[u];
    __syncthreads();
    if (s == 0) {
        float m0 = comb[0][lane][0], m1 = comb[1][lane][0];
        float m2 = comb[2][lane][0], m3 = comb[3][lane][0];
        float M = fmaxf(fmaxf(m0, m1), fmaxf(m2, m3));
        float w0 = __expf(m0 - M), w1 = __expf(m1 - M);
        float w2 = __expf(m2 - M), w3 = __expf(m3 - M);
        float L = comb[0][lane][1] * w0 + comb[1][lane][1] * w1 +
                  comb[2][lane][1] * w2 + comb[3][lane][1] * w3;
        float inv = 1.0f / L;
        float* op = Ao + ((size_t)(b * NN + q)) * HIDD + h * DHD;
#pragma unroll
        for (int u = 0; u < 8; u++) {
            float4 o4;
            o4.x = (comb[0][lane][2+u*4+0]*w0 + comb[1][lane][2+u*4+0]*w1 +
                    comb[2][lane][2+u*4+0]*w2 + comb[3][lane][2+u*4+0]*w3) * inv;
            o4.y = (comb[0][lane][2+u*4+1]*w0 + comb[1][lane][2+u*4+1]*w1 +
                    comb[2][lane][2+u*4+1]*w2 + comb[3][lane][2+u*4+1]*w3) * inv;
            o4.z = (comb[0][lane][2+u*4+2]*w0 + comb[1][lane][2+u*4+2]*w1 +
                    comb[2][lane][2+u*4+2]*w2 + comb[3][lane][2+u*4+2]*w3) * inv;
            o4.w = (comb[0][lane][2+u*4+3]*w0 + comb[1][lane][2+u*4+3]*w1 +
                    comb[2][lane][2+u*4+3]*w2 + comb[3][lane][2+u*4+3]*w3) * inv;
            ((float4*)op)[u] = o4;
        }
    }
}

// ---------------- TopK pool: scores + bitonic sort (per graph) ------------
__global__ __launch_bounds__(1024) void pool_topk(
    const float* __restrict__ xg, const float* __restrict__ w,
    float* __restrict__ out_perm, int* __restrict__ perm_int,
    float* __restrict__ vals_ws, int* __restrict__ nmap)
{
    __shared__ float wf[256];
    __shared__ float sv[1024];
    __shared__ unsigned long long keys[1024];
    __shared__ float nrm_s;
    int g = blockIdx.x, t = threadIdx.x;
    if (t < 256) wf[t] = w[t];
    nmap[g * 1024 + t] = -1;
    __syncthreads();
    if (t == 0) {
        float ss = 0.f;
        for (int c = 0; c < 256; c++) ss += wf[c] * wf[c];
        nrm_s = sqrtf(ss);
    }
    __syncthreads();
    float nrm = nrm_s;
    const float* xr = xg + ((size_t)(g * 1024 + t)) * 256;
    float dot = 0.f;
    for (int c = 0; c < 256; c += 4) {
        float4 x4 = *(const float4*)(xr + c);
        dot += x4.x * wf[c] + x4.y * wf[c + 1] + x4.z * wf[c + 2] + x4.w * wf[c + 3];
    }
    float s = tanhf(dot / nrm);
    sv[t] = s;
    unsigned u = __float_as_uint(s);
    u ^= (u >> 31) ? 0xFFFFFFFFu : 0x80000000u;
    keys[t] = (((unsigned long long)(~u)) << 32) | (unsigned)t;  // desc score, asc idx
    __syncthreads();
    for (unsigned k = 2; k <= 1024; k <<= 1) {
        for (unsigned j = k >> 1; j > 0; j >>= 1) {
            unsigned ixj = (unsigned)t ^ j;
            if (ixj > (unsigned)t) {
                unsigned long long a = keys[t], bb = keys[ixj];
                bool up = ((t & k) == 0);
                if (up ? (a > bb) : (a < bb)) { keys[t] = bb; keys[ixj] = a; }
            }
            __syncthreads();
        }
    }
    if (t < 512) {
        int idx = (int)(keys[t] & 1023u);
        out_perm[g * 512 + t] = (float)idx;
        perm_int[g * 512 + t] = idx;
        vals_ws[g * 512 + t] = sv[idx];
        nmap[g * 1024 + idx] = t;
    }
}

// ---------------- sub_x gather ------------------------------------------
__global__ __launch_bounds__(256) void gather_subx(
    const float* __restrict__ xg, const int* __restrict__ perm_int,
    const float* __restrict__ vals_ws, float* __restrict__ out_subx)
{
    int i4 = (blockIdx.x * 256 + threadIdx.x) * 4;   // < 1048576
    int b = i4 >> 17;
    int rem = i4 & 131071;
    int j = rem >> 8, c = rem & 255;
    int p = perm_int[b * 512 + j];
    float v = vals_ws[b * 512 + j];
    float4 x4 = *(const float4*)(xg + ((size_t)(b * 1024 + p)) * 256 + c);
    float4 o = {x4.x * v, x4.y * v, x4.z * v, x4.w * v};
    *(float4*)(out_subx + i4) = o;
}

// ---------------- Edge pipeline -----------------------------------------
__global__ __launch_bounds__(256) void zero_hist(int4* __restrict__ h) {
    h[blockIdx.x * 256 + threadIdx.x] = make_int4(0, 0, 0, 0);
}

__global__ __launch_bounds__(256) void edge_map(
    const int* __restrict__ e0, const int* __restrict__ e1,
    const int* __restrict__ nmap, int* __restrict__ H,
    int* __restrict__ key_e, int* __restrict__ r_e)
{
    int i = blockIdx.x * 256 + threadIdx.x;  // < 131072
    int g = i >> 14;
    int su = e0[i] - (g << 10);
    int sd = e1[i] - (g << 10);
    int nu = nmap[(g << 10) + su];
    int nv = nmap[(g << 10) + sd];
    if (nu >= 0 && nv >= 0) {
        int key = (nu << 9) | nv;
        int r = atomicAdd(&H[g * 262144 + key], 1);
        key_e[i] = key; r_e[i] = r;
    } else {
        key_e[i] = -1;
    }
}

__global__ __launch_bounds__(256) void scan_chunks(int* __restrict__ H,
                                                   int* __restrict__ ctot)
{
    __shared__ int scl[256];
    int t = threadIdx.x, blk = blockIdx.x;          // blk = g*256 + chunk
    int base = blk * 1024;
    int4 v = *(int4*)&H[base + t * 4];
    int s = v.x + v.y + v.z + v.w;
    scl[t] = s;
    __syncthreads();
    for (int off = 1; off < 256; off <<= 1) {
        int add = (t >= off) ? scl[t - off] : 0;
        __syncthreads();
        scl[t] += add;
        __syncthreads();
    }
    int incl = scl[t], excl = incl - s;
    int4 o; o.x = excl; o.y = excl + v.x; o.z = o.y + v.y; o.w = o.z + v.z;
    *(int4*)&H[base + t * 4] = o;
    if (t == 255) ctot[blk] = incl;
}

__global__ __launch_bounds__(256) void scan_tots(const int* __restrict__ ctot,
                                                 int* __restrict__ cbase)
{
    __shared__ int scl[256];
    int g = blockIdx.x, t = threadIdx.x;
    int v = ctot[g * 256 + t];
    scl[t] = v;
    __syncthreads();
    for (int off = 1; off < 256; off <<= 1) {
        int add = (t >= off) ? scl[t - off] : 0;
        __syncthreads();
        scl[t] += add;
        __syncthreads();
    }
    cbase[g * 256 + t] = scl[t] - v;
}

__global__ __launch_bounds__(256) void edge_out_init(float* __restrict__ o)
{
    int i = blockIdx.x * 256 + threadIdx.x;  // < 393216
    if (i < 262144) o[OUT_SUBE + i] = -1.0f;
    else            o[OUT_VALID + (i - 262144)] = 0.0f;
}

__global__ __launch_bounds__(256) void edge_out_write(
    const int* __restrict__ key_e, const int* __restrict__ r_e,
    const int* __restrict__ H, const int* __restrict__ cbase,
    float* __restrict__ o)
{
    int i = blockIdx.x * 256 + threadIdx.x;
    int key = key_e[i];
    if (key < 0) return;
    int g = i >> 14;
    int pos = H[g * 262144 + key] + cbase[(g << 8) + (key >> 10)] + r_e[i];
    int nu = key >> 9, nv = key & 511;
    o[OUT_SUBE + (g * 2 + 0) * 16384 + pos] = (float)nu;
    o[OUT_SUBE + (g * 2 + 1) * 16384 + pos] = (float)nv;
    o[OUT_VALID + g * 16384 + pos] = 1.0f;
}

// -------------------------------------------------------------------------
extern "C" void kernel_launch(void* const* d_in, const int* in_sizes, int n_in,
                              void* d_out, int out_size, void* d_ws, size_t ws_size,
                              hipStream_t stream)
{
    const float* x    = (const float*)d_in[0];
    const int*   eidx = (const int*)d_in[1];
    const float* dist = (const float*)d_in[3];
    const float* Wq   = (const float*)d_in[5];
    const float* Wk   = (const float*)d_in[6];
    const float* Wv   = (const float*)d_in[7];
    const float* Wo   = (const float*)d_in[8];
    const float* tw   = (const float*)d_in[9];

    char* ws = (char*)d_ws;
    // Region A [0,8MB): Q, later xg (f32 encoder result)
    // Region B [8,16MB): K, later hist
    // Region C [16,24MB): V, later edge scratch + pool scratch
    // Region D [24,32MB): attn_out
    float* Qf = (float*)(ws);
    float* Kf = (float*)(ws + (8u << 20));
    float* Vf = (float*)(ws + (16u << 20));
    float* Ao = (float*)(ws + (24u << 20));
    float* xg = Qf;
    int*   H  = (int*)Kf;
    char*  cb = ws + (16u << 20);
    int*   key_e = (int*)(cb);
    int*   r_e   = (int*)(cb + (512u << 10));
    int*   ctot  = (int*)(cb + (1024u << 10));
    int*   cbas  = (int*)(cb + (1024u << 10) + 8192);
    int*   permi = (int*)(cb + (1024u << 10) + 16384);
    float* vals  = (float*)(cb + (1024u << 10) + 32768);
    int*   nmap  = (int*)(cb + (1024u << 10) + 49152);
    float* out = (float*)d_out;

    gemm_qkv<<<1536, 256, 0, stream>>>(x, Wq, Wk, Wv, Qf, Kf, Vf);
    attn_split<<<1024, 256, 0, stream>>>(Qf, Kf, Vf, dist, Ao);
    gemm_f32_dual<<<512, 256, 0, stream>>>(Ao, Wo, xg, out + OUT_ENC);
    pool_topk<<<8, 1024, 0, stream>>>(xg, tw, out + OUT_PERM, permi, vals, nmap);
    zero_hist<<<2048, 256, 0, stream>>>((int4*)H);
    edge_map<<<512, 256, 0, stream>>>(eidx, eidx + 131072, nmap, H, key_e, r_e);
    scan_chunks<<<2048, 256, 0, stream>>>(H, ctot);
    scan_tots<<<8, 256, 0, stream>>>(ctot, cbas);
    edge_out_init<<<1536, 256, 0, stream>>>(out);
    edge_out_write<<<512, 256, 0, stream>>>(key_e, r_e, H, cbas, out);
    gather_subx<<<1024, 256, 0, stream>>>(xg, permi, vals, out + OUT_SUBX);
}

// Round 7
// 480.068 us; speedup vs baseline: 4.4471x; 2.4415x over previous
//
#include <hip/hip_runtime.h>
#include <hip/hip_bf16.h>
#include <math.h>

// Sizes (fixed by the problem)
#define NB   8
#define NN   1024
#define HIDD 256
#define NHD  8
#define DHD  32
#define EPG  16384
#define KTOP 512

// out layout (f32 elements)
#define OUT_ENC   0
#define OUT_SUBX  2097152
#define OUT_SUBE  3145728
#define OUT_PERM  3407872
#define OUT_VALID 3411968

// ---------------- Fused QKV GEMM: 3x [8192x256]@[256x256] -----------------
__global__ __launch_bounds__(256) void gemm_qkv(
    const float* __restrict__ A,
    const float* __restrict__ W0, const float* __restrict__ W1,
    const float* __restrict__ W2,
    float* __restrict__ C0, float* __restrict__ C1, float* __restrict__ C2)
{
    __shared__ float As[32][68];
    __shared__ float Bs[32][68];
    int which = blockIdx.x >> 9;                 // 0,1,2
    const float* W = (which == 0) ? W0 : ((which == 1) ? W1 : W2);
    float*       C = (which == 0) ? C0 : ((which == 1) ? C1 : C2);
    int bid = blockIdx.x & 511;
    int t  = threadIdx.x;
    int bm = bid >> 2, bn = bid & 3;
    int m0 = bm * 64, n0 = bn * 64;
    int tx = t & 15, ty = t >> 4;
    float acc[4][4];
#pragma unroll
    for (int i = 0; i < 4; i++)
#pragma unroll
        for (int j = 0; j < 4; j++) acc[i][j] = 0.f;
    int am = t >> 2, ak = (t & 3) * 8;
    int bk = t >> 3, bn2 = (t & 7) * 8;
    for (int k0 = 0; k0 < 256; k0 += 32) {
        __syncthreads();
        float4 a0 = *(const float4*)(A + (m0 + am) * 256 + k0 + ak);
        float4 a1 = *(const float4*)(A + (m0 + am) * 256 + k0 + ak + 4);
        float4 b0 = *(const float4*)(W + (k0 + bk) * 256 + n0 + bn2);
        float4 b1 = *(const float4*)(W + (k0 + bk) * 256 + n0 + bn2 + 4);
        As[ak + 0][am] = a0.x; As[ak + 1][am] = a0.y;
        As[ak + 2][am] = a0.z; As[ak + 3][am] = a0.w;
        As[ak + 4][am] = a1.x; As[ak + 5][am] = a1.y;
        As[ak + 6][am] = a1.z; As[ak + 7][am] = a1.w;
        Bs[bk][bn2 + 0] = b0.x; Bs[bk][bn2 + 1] = b0.y;
        Bs[bk][bn2 + 2] = b0.z; Bs[bk][bn2 + 3] = b0.w;
        Bs[bk][bn2 + 4] = b1.x; Bs[bk][bn2 + 5] = b1.y;
        Bs[bk][bn2 + 6] = b1.z; Bs[bk][bn2 + 7] = b1.w;
        __syncthreads();
#pragma unroll
        for (int kk = 0; kk < 32; kk++) {
            float4 a4 = *(const float4*)&As[kk][ty * 4];
            float4 b4 = *(const float4*)&Bs[kk][tx * 4];
            float aa[4] = {a4.x, a4.y, a4.z, a4.w};
            float bb[4] = {b4.x, b4.y, b4.z, b4.w};
#pragma unroll
            for (int i = 0; i < 4; i++)
#pragma unroll
                for (int j = 0; j < 4; j++) acc[i][j] += aa[i] * bb[j];
        }
    }
#pragma unroll
    for (int i = 0; i < 4; i++) {
        float4 o = {acc[i][0], acc[i][1], acc[i][2], acc[i][3]};
        *(float4*)(C + (m0 + ty * 4 + i) * 256 + n0 + tx * 4) = o;
    }
}

// ------ GEMM writing two copies: xg (ws) and out ENC region (both f32) ----
__global__ __launch_bounds__(256) void gemm_f32_dual(
    const float* __restrict__ A, const float* __restrict__ W,
    float* __restrict__ Cf, float* __restrict__ Co)
{
    __shared__ float As[32][68];
    __shared__ float Bs[32][68];
    int t  = threadIdx.x;
    int bm = blockIdx.x >> 2, bn = blockIdx.x & 3;
    int m0 = bm * 64, n0 = bn * 64;
    int tx = t & 15, ty = t >> 4;
    float acc[4][4];
#pragma unroll
    for (int i = 0; i < 4; i++)
#pragma unroll
        for (int j = 0; j < 4; j++) acc[i][j] = 0.f;
    int am = t >> 2, ak = (t & 3) * 8;
    int bk = t >> 3, bn2 = (t & 7) * 8;
    for (int k0 = 0; k0 < 256; k0 += 32) {
        __syncthreads();
        float4 a0 = *(const float4*)(A + (m0 + am) * 256 + k0 + ak);
        float4 a1 = *(const float4*)(A + (m0 + am) * 256 + k0 + ak + 4);
        float4 b0 = *(const float4*)(W + (k0 + bk) * 256 + n0 + bn2);
        float4 b1 = *(const float4*)(W + (k0 + bk) * 256 + n0 + bn2 + 4);
        As[ak + 0][am] = a0.x; As[ak + 1][am] = a0.y;
        As[ak + 2][am] = a0.z; As[ak + 3][am] = a0.w;
        As[ak + 4][am] = a1.x; As[ak + 5][am] = a1.y;
        As[ak + 6][am] = a1.z; As[ak + 7][am] = a1.w;
        Bs[bk][bn2 + 0] = b0.x; Bs[bk][bn2 + 1] = b0.y;
        Bs[bk][bn2 + 2] = b0.z; Bs[bk][bn2 + 3] = b0.w;
        Bs[bk][bn2 + 4] = b1.x; Bs[bk][bn2 + 5] = b1.y;
        Bs[bk][bn2 + 6] = b1.z; Bs[bk][bn2 + 7] = b1.w;
        __syncthreads();
#pragma unroll
        for (int kk = 0; kk < 32; kk++) {
            float4 a4 = *(const float4*)&As[kk][ty * 4];
            float4 b4 = *(const float4*)&Bs[kk][tx * 4];
            float aa[4] = {a4.x, a4.y, a4.z, a4.w};
            float bb[4] = {b4.x, b4.y, b4.z, b4.w};
#pragma unroll
            for (int i = 0; i < 4; i++)
#pragma unroll
                for (int j = 0; j < 4; j++) acc[i][j] += aa[i] * bb[j];
        }
    }
#pragma unroll
    for (int i = 0; i < 4; i++) {
        int row = m0 + ty * 4 + i, col = n0 + tx * 4;
        float4 o = {acc[i][0], acc[i][1], acc[i][2], acc[i][3]};
        *(float4*)(Cf + row * 256 + col) = o;
        *(float4*)(Co + row * 256 + col) = o;
    }
}

// -------- Attention: split-K flash, 4 waves = 4 k-splits per block --------
// FP sequence IDENTICAL to R5 (tile=32, split 4x256, same combine) -- R6
// proved the topk ranking is sensitive to the summation order; do not alter.
// Data path changed only: K/V tiles staged to per-wave LDS with coalesced
// per-lane loads; dot loop reads LDS broadcast (conflict-free). Per-wave
// stage region (2048 f) aliases that wave's own combine slab (2176 f), so
// total LDS stays 34816 B -> 4 blocks/CU; waves_per_eu(4) caps VGPR at 128
// (live state ~105, no spill) -> 16 waves/CU.
__global__ __launch_bounds__(256) __attribute__((amdgpu_waves_per_eu(4)))
void attn_split(
    const float* __restrict__ Q, const float* __restrict__ Kf,
    const float* __restrict__ Vf, const float* __restrict__ dist,
    float* __restrict__ Ao)
{
    __shared__ float smem[4 * 2176];
    int blk = blockIdx.x;                        // 1024 = 8 * 8 * 16
    int b = blk >> 7, h = (blk >> 4) & 7, qc = blk & 15;
    int t = threadIdx.x;
    int lane = t & 63, s = t >> 6;
    int q = qc * 64 + lane;
    float* ks = smem + s * 2176;                 // 1024 f K tile
    float* vs = ks + 1024;                       // 1024 f V tile
    int srow = lane >> 3;                        // staging: row base 0..7
    int scol = (lane & 7) * 4;                   // staging: col 0,4,...,28
    const float* qp = Q + ((size_t)(b * NN + q)) * HIDD + h * DHD;
    float qv[32], acc[32];
#pragma unroll
    for (int u = 0; u < 8; u++) {
        float4 v4 = ((const float4*)qp)[u];
        qv[u * 4 + 0] = v4.x; qv[u * 4 + 1] = v4.y;
        qv[u * 4 + 2] = v4.z; qv[u * 4 + 3] = v4.w;
    }
#pragma unroll
    for (int u = 0; u < 32; u++) acc[u] = 0.f;
    float m = -INFINITY, l = 0.f;
    const float* dp = dist + ((size_t)(b * NN + q)) * NN;
    const float SCALE = 0.17677669529663687f;    // 1/sqrt(32)
    int kbeg = s * 256;
    for (int k0 = kbeg; k0 < kbeg + 256; k0 += 32) {
        // ---- stage K,V 32x32 tiles into this wave's LDS region ----------
        const float* kgb = Kf + ((size_t)(b * NN + k0)) * HIDD + h * DHD;
        const float* vgb = Vf + ((size_t)(b * NN + k0)) * HIDD + h * DHD;
#pragma unroll
        for (int j = 0; j < 4; j++) {
            int row = srow + j * 8;
            *(float4*)(ks + row * 32 + scol) =
                *(const float4*)(kgb + row * 256 + scol);
            *(float4*)(vs + row * 32 + scol) =
                *(const float4*)(vgb + row * 256 + scol);
        }
        // wave-synchronous: DS pipe is in-order within a wave, no barrier
        float sc[32];
#pragma unroll
        for (int i = 0; i < 8; i++) {
            float4 dv = ((const float4*)(dp + k0))[i];
            sc[i * 4 + 0] = dv.x; sc[i * 4 + 1] = dv.y;
            sc[i * 4 + 2] = dv.z; sc[i * 4 + 3] = dv.w;
        }
#pragma unroll
        for (int kk = 0; kk < 32; kk++) {
            const float4* kr = (const float4*)(ks + kk * 32);
            float d = 0.f;
#pragma unroll
            for (int u = 0; u < 8; u++) {
                float4 kv = kr[u];
                d += qv[u * 4 + 0] * kv.x + qv[u * 4 + 1] * kv.y +
                     qv[u * 4 + 2] * kv.z + qv[u * 4 + 3] * kv.w;
            }
            sc[kk] += d * SCALE;
        }
        float tm = -INFINITY;
#pragma unroll
        for (int kk = 0; kk < 32; kk++) tm = fmaxf(tm, sc[kk]);
        float mnew = fmaxf(m, tm);
        float corr = __expf(m - mnew);
        l *= corr;
#pragma unroll
        for (int u = 0; u < 32; u++) acc[u] *= corr;
#pragma unroll
        for (int kk = 0; kk < 32; kk++) {
            float p = __expf(sc[kk] - mnew);
            l += p;
            const float4* vr = (const float4*)(vs + kk * 32);
#pragma unroll
            for (int u = 0; u < 8; u++) {
                float4 vv = vr[u];
                acc[u * 4 + 0] += p * vv.x; acc[u * 4 + 1] += p * vv.y;
                acc[u * 4 + 2] += p * vv.z; acc[u * 4 + 3] += p * vv.w;
            }
        }
        m = mnew;
    }
    // combine slab aliases this wave's own stage region (done reading it)
    float* cb0 = smem + s * 2176 + lane * 34;
    cb0[0] = m;
    cb0[1] = l;
#pragma unroll
    for (int u = 0; u < 32; u++) cb0[2 + u] = acc[u];
    __syncthreads();
    if (s == 0) {
        const float* c0 = smem + 0 * 2176 + lane * 34;
        const float* c1 = smem + 1 * 2176 + lane * 34;
        const float* c2 = smem + 2 * 2176 + lane * 34;
        const float* c3 = smem + 3 * 2176 + lane * 34;
        float m0 = c0[0], m1 = c1[0], m2 = c2[0], m3 = c3[0];
        float M = fmaxf(fmaxf(m0, m1), fmaxf(m2, m3));
        float w0 = __expf(m0 - M), w1 = __expf(m1 - M);
        float w2 = __expf(m2 - M), w3 = __expf(m3 - M);
        float L = c0[1] * w0 + c1[1] * w1 + c2[1] * w2 + c3[1] * w3;
        float inv = 1.0f / L;
        float* op = Ao + ((size_t)(b * NN + q)) * HIDD + h * DHD;
#pragma unroll
        for (int u = 0; u < 8; u++) {
            float4 o4;
            o4.x = (c0[2+u*4+0]*w0 + c1[2+u*4+0]*w1 +
                    c2[2+u*4+0]*w2 + c3[2+u*4+0]*w3) * inv;
            o4.y = (c0[2+u*4+1]*w0 + c1[2+u*4+1]*w1 +
                    c2[2+u*4+1]*w2 + c3[2+u*4+1]*w3) * inv;
            o4.z = (c0[2+u*4+2]*w0 + c1[2+u*4+2]*w1 +
                    c2[2+u*4+2]*w2 + c3[2+u*4+2]*w3) * inv;
            o4.w = (c0[2+u*4+3]*w0 + c1[2+u*4+3]*w1 +
                    c2[2+u*4+3]*w2 + c3[2+u*4+3]*w3) * inv;
            ((float4*)op)[u] = o4;
        }
    }
}

// ---------------- TopK pool: scores + bitonic sort (per graph) ------------
__global__ __launch_bounds__(1024) void pool_topk(
    const float* __restrict__ xg, const float* __restrict__ w,
    float* __restrict__ out_perm, int* __restrict__ perm_int,
    float* __restrict__ vals_ws, int* __restrict__ nmap)
{
    __shared__ float wf[256];
    __shared__ float sv[1024];
    __shared__ unsigned long long keys[1024];
    __shared__ float nrm_s;
    int g = blockIdx.x, t = threadIdx.x;
    if (t < 256) wf[t] = w[t];
    nmap[g * 1024 + t] = -1;
    __syncthreads();
    if (t == 0) {
        float ss = 0.f;
        for (int c = 0; c < 256; c++) ss += wf[c] * wf[c];
        nrm_s = sqrtf(ss);
    }
    __syncthreads();
    float nrm = nrm_s;
    const float* xr = xg + ((size_t)(g * 1024 + t)) * 256;
    float dot = 0.f;
    for (int c = 0; c < 256; c += 4) {
        float4 x4 = *(const float4*)(xr + c);
        dot += x4.x * wf[c] + x4.y * wf[c + 1] + x4.z * wf[c + 2] + x4.w * wf[c + 3];
    }
    float s = tanhf(dot / nrm);
    sv[t] = s;
    unsigned u = __float_as_uint(s);
    u ^= (u >> 31) ? 0xFFFFFFFFu : 0x80000000u;
    keys[t] = (((unsigned long long)(~u)) << 32) | (unsigned)t;  // desc score, asc idx
    __syncthreads();
    for (unsigned k = 2; k <= 1024; k <<= 1) {
        for (unsigned j = k >> 1; j > 0; j >>= 1) {
            unsigned ixj = (unsigned)t ^ j;
            if (ixj > (unsigned)t) {
                unsigned long long a = keys[t], bb = keys[ixj];
                bool up = ((t & k) == 0);
                if (up ? (a > bb) : (a < bb)) { keys[t] = bb; keys[ixj] = a; }
            }
            __syncthreads();
        }
    }
    if (t < 512) {
        int idx = (int)(keys[t] & 1023u);
        out_perm[g * 512 + t] = (float)idx;
        perm_int[g * 512 + t] = idx;
        vals_ws[g * 512 + t] = sv[idx];
        nmap[g * 1024 + idx] = t;
    }
}

// ---------------- sub_x gather ------------------------------------------
__global__ __launch_bounds__(256) void gather_subx(
    const float* __restrict__ xg, const int* __restrict__ perm_int,
    const float* __restrict__ vals_ws, float* __restrict__ out_subx)
{
    int i4 = (blockIdx.x * 256 + threadIdx.x) * 4;   // < 1048576
    int b = i4 >> 17;
    int rem = i4 & 131071;
    int j = rem >> 8, c = rem & 255;
    int p = perm_int[b * 512 + j];
    float v = vals_ws[b * 512 + j];
    float4 x4 = *(const float4*)(xg + ((size_t)(b * 1024 + p)) * 256 + c);
    float4 o = {x4.x * v, x4.y * v, x4.z * v, x4.w * v};
    *(float4*)(out_subx + i4) = o;
}

// ---------------- Edge pipeline -----------------------------------------
__global__ __launch_bounds__(256) void zero_hist(int4* __restrict__ h) {
    h[blockIdx.x * 256 + threadIdx.x] = make_int4(0, 0, 0, 0);
}

__global__ __launch_bounds__(256) void edge_map(
    const int* __restrict__ e0, const int* __restrict__ e1,
    const int* __restrict__ nmap, int* __restrict__ H,
    int* __restrict__ key_e, int* __restrict__ r_e)
{
    int i = blockIdx.x * 256 + threadIdx.x;  // < 131072
    int g = i >> 14;
    int su = e0[i] - (g << 10);
    int sd = e1[i] - (g << 10);
    int nu = nmap[(g << 10) + su];
    int nv = nmap[(g << 10) + sd];
    if (nu >= 0 && nv >= 0) {
        int key = (nu << 9) | nv;
        int r = atomicAdd(&H[g * 262144 + key], 1);
        key_e[i] = key; r_e[i] = r;
    } else {
        key_e[i] = -1;
    }
}

__global__ __launch_bounds__(256) void scan_chunks(int* __restrict__ H,
                                                   int* __restrict__ ctot)
{
    __shared__ int scl[256];
    int t = threadIdx.x, blk = blockIdx.x;          // blk = g*256 + chunk
    int base = blk * 1024;
    int4 v = *(int4*)&H[base + t * 4];
    int s = v.x + v.y + v.z + v.w;
    scl[t] = s;
    __syncthreads();
    for (int off = 1; off < 256; off <<= 1) {
        int add = (t >= off) ? scl[t - off] : 0;
        __syncthreads();
        scl[t] += add;
        __syncthreads();
    }
    int incl = scl[t], excl = incl - s;
    int4 o; o.x = excl; o.y = excl + v.x; o.z = o.y + v.y; o.w = o.z + v.z;
    *(int4*)&H[base + t * 4] = o;
    if (t == 255) ctot[blk] = incl;
}

__global__ __launch_bounds__(256) void scan_tots(const int* __restrict__ ctot,
                                                 int* __restrict__ cbase)
{
    __shared__ int scl[256];
    int g = blockIdx.x, t = threadIdx.x;
    int v = ctot[g * 256 + t];
    scl[t] = v;
    __syncthreads();
    for (int off = 1; off < 256; off <<= 1) {
        int add = (t >= off) ? scl[t - off] : 0;
        __syncthreads();
        scl[t] += add;
        __syncthreads();
    }
    cbase[g * 256 + t] = scl[t] - v;
}

__global__ __launch_bounds__(256) void edge_out_init(float* __restrict__ o)
{
    int i = blockIdx.x * 256 + threadIdx.x;  // < 393216
    if (i < 262144) o[OUT_SUBE + i] = -1.0f;
    else            o[OUT_VALID + (i - 262144)] = 0.0f;
}

__global__ __launch_bounds__(256) void edge_out_write(
    const int* __restrict__ key_e, const int* __restrict__ r_e,
    const int* __restrict__ H, const int* __restrict__ cbase,
    float* __restrict__ o)
{
    int i = blockIdx.x * 256 + threadIdx.x;
    int key = key_e[i];
    if (key < 0) return;
    int g = i >> 14;
    int pos = H[g * 262144 + key] + cbase[(g << 8) + (key >> 10)] + r_e[i];
    int nu = key >> 9, nv = key & 511;
    o[OUT_SUBE + (g * 2 + 0) * 16384 + pos] = (float)nu;
    o[OUT_SUBE + (g * 2 + 1) * 16384 + pos] = (float)nv;
    o[OUT_VALID + g * 16384 + pos] = 1.0f;
}

// -------------------------------------------------------------------------
extern "C" void kernel_launch(void* const* d_in, const int* in_sizes, int n_in,
                              void* d_out, int out_size, void* d_ws, size_t ws_size,
                              hipStream_t stream)
{
    const float* x    = (const float*)d_in[0];
    const int*   eidx = (const int*)d_in[1];
    const float* dist = (const float*)d_in[3];
    const float* Wq   = (const float*)d_in[5];
    const float* Wk   = (const float*)d_in[6];
    const float* Wv   = (const float*)d_in[7];
    const float* Wo   = (const float*)d_in[8];
    const float* tw   = (const float*)d_in[9];

    char* ws = (char*)d_ws;
    // Region A [0,8MB): Q, later xg (f32 encoder result)
    // Region B [8,16MB): K, later hist
    // Region C [16,24MB): V, later edge scratch + pool scratch
    // Region D [24,32MB): attn_out
    float* Qf = (float*)(ws);
    float* Kf = (float*)(ws + (8u << 20));
    float* Vf = (float*)(ws + (16u << 20));
    float* Ao = (float*)(ws + (24u << 20));
    float* xg = Qf;
    int*   H  = (int*)Kf;
    char*  cb = ws + (16u << 20);
    int*   key_e = (int*)(cb);
    int*   r_e   = (int*)(cb + (512u << 10));
    int*   ctot  = (int*)(cb + (1024u << 10));
    int*   cbas  = (int*)(cb + (1024u << 10) + 8192);
    int*   permi = (int*)(cb + (1024u << 10) + 16384);
    float* vals  = (float*)(cb + (1024u << 10) + 32768);
    int*   nmap  = (int*)(cb + (1024u << 10) + 49152);
    float* out = (float*)d_out;

    gemm_qkv<<<1536, 256, 0, stream>>>(x, Wq, Wk, Wv, Qf, Kf, Vf);
    attn_split<<<1024, 256, 0, stream>>>(Qf, Kf, Vf, dist, Ao);
    gemm_f32_dual<<<512, 256, 0, stream>>>(Ao, Wo, xg, out + OUT_ENC);
    pool_topk<<<8, 1024, 0, stream>>>(xg, tw, out + OUT_PERM, permi, vals, nmap);
    zero_hist<<<2048, 256, 0, stream>>>((int4*)H);
    edge_map<<<512, 256, 0, stream>>>(eidx, eidx + 131072, nmap, H, key_e, r_e);
    scan_chunks<<<2048, 256, 0, stream>>>(H, ctot);
    scan_tots<<<8, 256, 0, stream>>>(ctot, cbas);
    edge_out_init<<<1536, 256, 0, stream>>>(out);
    edge_out_write<<<512, 256, 0, stream>>>(key_e, r_e, H, cbas, out);
    gather_subx<<<1024, 256, 0, stream>>>(xg, permi, vals, out + OUT_SUBX);
}